// Round 4
// baseline (138.931 us; speedup 1.0000x reference)
//
#include <hip/hip_runtime.h>
#include <math.h>

#define BT 32768   // B*T tokens
#define DD 1024    // feature dim
#define NN 512     // buffer slots
#define PP 1024    // partial-sum blocks

typedef float v4f __attribute__((ext_vector_type(4)));

__device__ __forceinline__ float fast_gelu(float x) {
    // 0.5*x*(1+tanh(c*(x+0.044715 x^3))), tanh(u) = 1 - 2/(exp(2u)+1)
    float u = 0.7978845608028654f * (x + 0.044715f * x * x * x);
    float e = __expf(2.0f * u);
    float t = 1.0f - __fdividef(2.0f, e + 1.0f);
    return 0.5f * x * (1.0f + t);
}

__device__ __forceinline__ void nt_store4(v4f* p, v4f v) {
    __builtin_nontemporal_store(v, p);  // no-allocate: don't evict x from L3
}

// Kernel 1: per-column partial sums of gelu(x). Block b sums rows [32b,32b+32).
// Regular loads on purpose: allocate x into L3 so pass 2 hits cache.
// Block 0 also zeroes the finisher counters for kernels 2/3 (visible at kernel boundary).
__global__ __launch_bounds__(256) void k_partial(const v4f* __restrict__ x4,
                                                 v4f* __restrict__ part,
                                                 int* __restrict__ cnts) {
    if (blockIdx.x == 0 && threadIdx.x == 0) { cnts[0] = 0; cnts[1] = 0; }
    int t = threadIdx.x;
    v4f acc = {0.f, 0.f, 0.f, 0.f};
    int base = blockIdx.x * 32 * (DD / 4) + t;  // 32 contiguous rows per block
    #pragma unroll 4
    for (int k = 0; k < 32; ++k) {
        v4f v = x4[base + k * (DD / 4)];
        acc.x += fast_gelu(v.x);
        acc.y += fast_gelu(v.y);
        acc.z += fast_gelu(v.z);
        acc.w += fast_gelu(v.w);
    }
    part[blockIdx.x * (DD / 4) + t] = acc;
}

// Kernel 2: 64 blocks reduce part[1024][1024] -> part2[64][1024]; last block to
// finish computes mean, norm, m_n.
__global__ __launch_bounds__(256) void k_reduce_mean(const float* __restrict__ part,
                                                     float* __restrict__ part2,
                                                     float* __restrict__ m_mean,
                                                     float* __restrict__ m_n,
                                                     float* __restrict__ nm_out,
                                                     int* __restrict__ cnts) {
    int t = threadIdx.x, j = blockIdx.x;
    float a0 = 0, a1 = 0, a2 = 0, a3 = 0;
    for (int r = 0; r < 16; ++r) {
        const float* row = part + (j * 16 + r) * DD;
        a0 += row[t];
        a1 += row[t + 256];
        a2 += row[t + 512];
        a3 += row[t + 768];
    }
    part2[j * DD + t] = a0;
    part2[j * DD + t + 256] = a1;
    part2[j * DD + t + 512] = a2;
    part2[j * DD + t + 768] = a3;
    __threadfence();
    __shared__ int sLast;
    if (t == 0) {
        int old = __hip_atomic_fetch_add(&cnts[0], 1, __ATOMIC_ACQ_REL, __HIP_MEMORY_SCOPE_AGENT);
        sLast = (old == 63) ? 1 : 0;
    }
    __syncthreads();
    if (!sLast) return;
    __threadfence();
    float s0 = 0, s1 = 0, s2 = 0, s3 = 0;
    for (int jj = 0; jj < 64; ++jj) {
        const float* row = part2 + jj * DD;
        s0 += row[t];
        s1 += row[t + 256];
        s2 += row[t + 512];
        s3 += row[t + 768];
    }
    const float inv = 1.0f / 32768.0f;
    float m0 = s0 * inv, m1 = s1 * inv, m2 = s2 * inv, m3 = s3 * inv;
    m_mean[t] = m0;
    m_mean[t + 256] = m1;
    m_mean[t + 512] = m2;
    m_mean[t + 768] = m3;
    __shared__ float red[256];
    red[t] = m0 * m0 + m1 * m1 + m2 * m2 + m3 * m3;
    __syncthreads();
    for (int st = 128; st > 0; st >>= 1) {
        if (t < st) red[t] += red[t + st];
        __syncthreads();
    }
    float nm = sqrtf(red[0]);
    float den = fmaxf(nm, 1e-12f);
    m_n[t] = m0 / den;
    m_n[t + 256] = m1 / den;
    m_n[t + 512] = m2 / den;
    m_n[t + 768] = m3 / den;
    if (t == 0) nm_out[0] = nm;
}

// Kernel 3: 512 blocks compute dot[n], sq[n]; last block does argmax
// (first-index tie-break), gate, and small state outputs.
__global__ __launch_bounds__(256) void k_sims_state(const v4f* __restrict__ buf4,
                                                    const float* __restrict__ m_meanf,
                                                    const float* __restrict__ nm_p,
                                                    const float* __restrict__ depl,
                                                    const int* __restrict__ hits,
                                                    const int* __restrict__ mask,
                                                    const float* __restrict__ logk,
                                                    const float* __restrict__ loglam,
                                                    const int* __restrict__ ptrp,
                                                    float* __restrict__ dot,
                                                    float* __restrict__ sq,
                                                    float* __restrict__ out_depl,
                                                    float* __restrict__ out_hits,
                                                    float* __restrict__ out_mask,
                                                    float* __restrict__ gate_p,
                                                    int* __restrict__ cnts) {
    int t = threadIdx.x, n = blockIdx.x;
    const v4f* m4 = (const v4f*)m_meanf;
    v4f b = buf4[n * (DD / 4) + t];
    v4f m = m4[t];
    float d = b.x * m.x + b.y * m.y + b.z * m.z + b.w * m.w;
    float q = b.x * b.x + b.y * b.y + b.z * b.z + b.w * b.w;
    __shared__ float rd[256], rq[256];
    rd[t] = d;
    rq[t] = q;
    __syncthreads();
    for (int st = 128; st > 0; st >>= 1) {
        if (t < st) { rd[t] += rd[t + st]; rq[t] += rq[t + st]; }
        __syncthreads();
    }
    if (t == 0) { dot[n] = rd[0]; sq[n] = rq[0]; }
    __threadfence();
    __shared__ int sLast;
    if (t == 0) {
        int old = __hip_atomic_fetch_add(&cnts[1], 1, __ATOMIC_ACQ_REL, __HIP_MEMORY_SCOPE_AGENT);
        sLast = (old == NN - 1) ? 1 : 0;
    }
    __syncthreads();
    if (!sLast) return;
    __threadfence();

    // finisher: 256 threads handle rows t and t+256
    float nm = fmaxf(nm_p[0], 1e-12f);
    float sA = mask[t] ? dot[t] / (fmaxf(sqrtf(sq[t]), 1e-12f) * nm) : -1.0f;
    float sB = mask[t + 256] ? dot[t + 256] / (fmaxf(sqrtf(sq[t + 256]), 1e-12f) * nm) : -1.0f;
    float bs;
    int bi;
    if (sB > sA) { bs = sB; bi = t + 256; } else { bs = sA; bi = t; }
    __shared__ float sv[256];
    __shared__ int si[256];
    sv[t] = bs;
    si[t] = bi;
    __syncthreads();
    for (int st = 128; st > 0; st >>= 1) {
        if (t < st) {
            float o = sv[t + st];
            int oi = si[t + st];
            if (o > sv[t] || (o == sv[t] && oi < si[t])) { sv[t] = o; si[t] = oi; }
        }
        __syncthreads();
    }
    __shared__ int s_near, s_fired;
    if (t == 0) {
        int nearest = si[0];
        float msim = sv[0];
        float k_depl = fminf(fmaxf(expf(logk[0]), 0.1f), 5.0f);
        float lam = fminf(fmaxf(expf(loglam[0]), 0.1f), 3.0f);
        gate_p[0] = expf(-k_depl * (1.0f - depl[nearest]) - lam * (float)hits[nearest]);
        s_near = nearest;
        s_fired = (msim > 0.85f) ? 1 : 0;
    }
    __syncthreads();
    int ptr = ptrp[0];
    for (int k = 0; k < 2; ++k) {
        int nn = t + k * 256;
        float ndv = depl[nn];
        int nh = hits[nn];
        float nmsk = mask[nn] ? 1.0f : 0.0f;
        if (nn == s_near && s_fired) { ndv *= 0.5f; nh += 1; }
        if (nn == ptr) { ndv = 1.0f; nh = 0; nmsk = 1.0f; }
        out_depl[nn] = ndv;
        out_hits[nn] = (float)nh;
        out_mask[nn] = nmsk;
    }
}

// Kernel 4: blocks [0,2048): out = gelu(x)*gate, x read (L3-warm), NT store out.
//           blocks [2048,2080): new_buf = buf with row ptr = m_n.
__global__ __launch_bounds__(256) void k_outbuf(const v4f* __restrict__ x4,
                                                v4f* __restrict__ o4,
                                                const v4f* __restrict__ buf4,
                                                const v4f* __restrict__ mn4,
                                                v4f* __restrict__ ob4,
                                                const float* __restrict__ gate_p,
                                                const int* __restrict__ ptrp) {
    int t = threadIdx.x;
    if (blockIdx.x < 2048) {
        float g = gate_p[0];
        int base = blockIdx.x * 4096 + t;  // block covers contiguous 64 KB
        #pragma unroll 4
        for (int k = 0; k < 16; ++k) {
            int i = base + k * 256;
            v4f v = x4[i];
            v4f r;
            r.x = fast_gelu(v.x) * g;
            r.y = fast_gelu(v.y) * g;
            r.z = fast_gelu(v.z) * g;
            r.w = fast_gelu(v.w) * g;
            nt_store4(&o4[i], r);
        }
    } else {
        int b2 = blockIdx.x - 2048;  // 0..31
        int ptr = ptrp[0];
        for (int k = 0; k < 16; ++k) {
            int i = b2 * 4096 + k * 256 + t;  // 131072 float4 total
            int row = i >> 8;
            v4f v = (row == ptr) ? mn4[i & 255] : buf4[i];
            ob4[i] = v;
        }
    }
}

extern "C" void kernel_launch(void* const* d_in, const int* in_sizes, int n_in,
                              void* d_out, int out_size, void* d_ws, size_t ws_size,
                              hipStream_t stream) {
    const float* x = (const float*)d_in[0];
    const float* log_k = (const float*)d_in[1];
    const float* log_lambda = (const float*)d_in[2];
    const float* buf = (const float*)d_in[3];
    const float* depl = (const float*)d_in[4];
    const int* hits = (const int*)d_in[5];
    const int* mask = (const int*)d_in[6];  // bool pushed as int32
    const int* ptr = (const int*)d_in[7];

    float* out = (float*)d_out;
    float* out_buf = out + 33554432;      // N*D
    float* out_depl = out_buf + NN * DD;  // 512
    float* out_hits = out_depl + NN;      // 512
    float* out_mask = out_hits + NN;      // 512

    // small scratch in ws (~13 KB, proven size range)
    int* cnts = (int*)d_ws;          // [0]=kernel2 counter, [1]=kernel3 counter
    float* wsf = (float*)d_ws;
    float* m_mean = wsf + 16;        // 1024 (64 B aligned for v4f)
    float* m_n = wsf + 1040;         // 1024 (4160 B, 16-aligned)
    float* nm = wsf + 2064;          // 1
    float* gate = wsf + 2065;        // 1
    float* dot = wsf + 2080;         // 512
    float* sq = wsf + 2592;          // 512

    // big scratch lives in the output region, consumed before k_outbuf overwrites:
    float* part = out;                 // [1024][1024] = 4 MB
    float* part2 = out + 16777216;     // [64][1024] = 256 KB

    k_partial<<<dim3(PP), dim3(256), 0, stream>>>((const v4f*)x, (v4f*)part, cnts);
    k_reduce_mean<<<dim3(64), dim3(256), 0, stream>>>(part, part2, m_mean, m_n, nm, cnts);
    k_sims_state<<<dim3(NN), dim3(256), 0, stream>>>((const v4f*)buf, m_mean, nm, depl, hits,
                                                     mask, log_k, log_lambda, ptr,
                                                     dot, sq, out_depl, out_hits, out_mask,
                                                     gate, cnts);
    k_outbuf<<<dim3(2080), dim3(256), 0, stream>>>((const v4f*)x, (v4f*)out,
                                                   (const v4f*)buf, (const v4f*)m_n,
                                                   (v4f*)out_buf, gate, ptr);
}